// Round 1
// baseline (280.424 us; speedup 1.0000x reference)
//
#include <hip/hip_runtime.h>
#include <hip/hip_bf16.h>

#define NN    4096
#define FIN   512
#define NH1   128
#define NH    4
#define NH2   256
#define NH3   64
#define CAP   64          // max neighbors per row (mean ~17, 11+ sigma safe)
#define ALPHA 0.2f

// ---------------------------------------------------------------------------
// K0: repack W_att (h,f,o) -> Wcat (f, h*128+o)  row-major 512x512
// ---------------------------------------------------------------------------
__global__ void k_repack_watt(const float* __restrict__ W_att, float* __restrict__ Wcat) {
    int idx = blockIdx.x * 256 + threadIdx.x;          // f*512 + col
    if (idx >= FIN * (NH * NH1)) return;
    int f = idx >> 9;
    int col = idx & 511;
    int h = col >> 7;
    int o = col & 127;
    Wcat[idx] = W_att[h * (FIN * NH1) + f * NH1 + o];
}

// ---------------------------------------------------------------------------
// K1: build per-row neighbor lists from adj (wave per row, ordered, no atomics)
// ---------------------------------------------------------------------------
__global__ void k_build_csr(const float* __restrict__ adj, int* __restrict__ nbr,
                            int* __restrict__ cnt) {
    int row = blockIdx.x * (blockDim.x / 64) + (threadIdx.x / 64);
    int lane = threadIdx.x & 63;
    if (row >= NN) return;
    const float* arow = adj + (size_t)row * NN;
    int* out = nbr + row * CAP;
    int base = 0;
    for (int c0 = 0; c0 < NN; c0 += 64) {
        float v = arow[c0 + lane];
        bool pred = v > 0.0f;
        unsigned long long m = __ballot(pred);
        if (pred) {
            int pos = base + __popcll(m & ((1ull << lane) - 1ull));
            if (pos < CAP) out[pos] = c0 + lane;
        }
        base += __popcll(m);
    }
    if (lane == 0) cnt[row] = base < CAP ? base : CAP;
}

// ---------------------------------------------------------------------------
// K2: tiled fp32 GEMM  C[MxN] = A[MxK] @ B[KxN]   (all row-major, 64x64 tiles)
// ---------------------------------------------------------------------------
#define BM 64
#define BN 64
#define BK 16
__global__ __launch_bounds__(256) void k_gemm_f32(const float* __restrict__ A,
                                                  const float* __restrict__ B,
                                                  float* __restrict__ C,
                                                  int M, int N, int K) {
    __shared__ float As[BK][BM + 1];
    __shared__ float Bs[BK][BN + 1];
    const int tid = threadIdx.x;
    const int tr = tid >> 4;            // 0..15
    const int tc = tid & 15;            // 0..15
    const int row0 = blockIdx.y * BM;
    const int col0 = blockIdx.x * BN;
    float acc[4][4] = {};
    for (int k0 = 0; k0 < K; k0 += BK) {
        #pragma unroll
        for (int i = tid; i < BM * BK; i += 256) {
            int r = i >> 4, c = i & 15;
            As[c][r] = A[(size_t)(row0 + r) * K + k0 + c];
        }
        #pragma unroll
        for (int i = tid; i < BK * BN; i += 256) {
            int r = i >> 6, c = i & 63;
            Bs[r][c] = B[(size_t)(k0 + r) * N + col0 + c];
        }
        __syncthreads();
        #pragma unroll
        for (int kk = 0; kk < BK; ++kk) {
            float a[4], b[4];
            #pragma unroll
            for (int i = 0; i < 4; ++i) a[i] = As[kk][tr * 4 + i];
            #pragma unroll
            for (int j = 0; j < 4; ++j) b[j] = Bs[kk][tc * 4 + j];
            #pragma unroll
            for (int i = 0; i < 4; ++i)
                #pragma unroll
                for (int j = 0; j < 4; ++j)
                    acc[i][j] = fmaf(a[i], b[j], acc[i][j]);
        }
        __syncthreads();
    }
    #pragma unroll
    for (int i = 0; i < 4; ++i) {
        int r = row0 + tr * 4 + i;
        #pragma unroll
        for (int j = 0; j < 4; ++j) {
            int c = col0 + tc * 4 + j;
            if (r < M && c < N) C[(size_t)r * N + c] = acc[i][j];
        }
    }
}

// ---------------------------------------------------------------------------
// K3: attention scores s1[h][n], s2[h][n]  (block per node, wave per head)
// ---------------------------------------------------------------------------
__global__ void k_scores(const float* __restrict__ Whc, const float* __restrict__ a,
                         float* __restrict__ s1, float* __restrict__ s2) {
    int n = blockIdx.x;
    int h = threadIdx.x >> 6;
    int lane = threadIdx.x & 63;
    const float* wrow = Whc + (size_t)n * (NH * NH1) + h * NH1;
    const float* a1 = a + h * (2 * NH1);
    const float* a2 = a1 + NH1;
    float v1 = wrow[lane] * a1[lane] + wrow[lane + 64] * a1[lane + 64];
    float v2 = wrow[lane] * a2[lane] + wrow[lane + 64] * a2[lane + 64];
    #pragma unroll
    for (int off = 32; off; off >>= 1) {
        v1 += __shfl_down(v1, off);
        v2 += __shfl_down(v2, off);
    }
    if (lane == 0) {
        s1[h * NN + n] = v1;
        s2[h * NN + n] = v2;
    }
}

// ---------------------------------------------------------------------------
// K4: per-node attention softmax + aggregate + ReLU -> xr (N x 512)
//     block per node, wave h handles head h; lane j holds neighbor j
// ---------------------------------------------------------------------------
__global__ void k_attn(const float* __restrict__ Whc, const float* __restrict__ s1,
                       const float* __restrict__ s2, const int* __restrict__ nbr,
                       const int* __restrict__ cnt, float* __restrict__ xr) {
    int n = blockIdx.x;
    int h = threadIdx.x >> 6;
    int lane = threadIdx.x & 63;
    int c = cnt[n];
    const int* nb = nbr + n * CAP;
    int m = (lane < c) ? nb[lane] : 0;
    float e = -1e30f;
    float s1n = s1[h * NN + n];
    if (lane < c) {
        float t = s1n + s2[h * NN + m];
        e = (t >= 0.0f) ? t : ALPHA * t;
    }
    float mx = e;
    #pragma unroll
    for (int off = 32; off; off >>= 1) mx = fmaxf(mx, __shfl_xor(mx, off));
    float p = (lane < c) ? __expf(e - mx) : 0.0f;
    float s = p;
    #pragma unroll
    for (int off = 32; off; off >>= 1) s += __shfl_xor(s, off);
    p /= s;
    float acc0 = 0.0f, acc1 = 0.0f;
    for (int j = 0; j < c; ++j) {
        float pj = __shfl(p, j);
        int mj = __shfl(m, j);
        const float* w = Whc + (size_t)mj * (NH * NH1) + h * NH1;
        acc0 = fmaf(pj, w[lane], acc0);
        acc1 = fmaf(pj, w[lane + 64], acc1);
    }
    float* outp = xr + (size_t)n * (NH * NH1) + h * NH1;
    outp[lane]      = fmaxf(acc0, 0.0f);
    outp[lane + 64] = fmaxf(acc1, 0.0f);
}

// ---------------------------------------------------------------------------
// K5: out[n][c] = (relu of) sum over neighbors m of Y[m][c]   (adj values are 1.0)
// ---------------------------------------------------------------------------
__global__ void k_nbr_sum(const float* __restrict__ Y, const int* __restrict__ nbr,
                          const int* __restrict__ cnt, float* __restrict__ out,
                          int C, int do_relu) {
    int n = blockIdx.x;
    int c = cnt[n];
    const int* nb = nbr + n * CAP;
    for (int col = threadIdx.x; col < C; col += blockDim.x) {
        float acc = 0.0f;
        for (int j = 0; j < c; ++j) acc += Y[(size_t)nb[j] * C + col];
        out[(size_t)n * C + col] = do_relu ? fmaxf(acc, 0.0f) : acc;
    }
}

// ---------------------------------------------------------------------------
// K6: final: g2 = nbrsum(y2); write g2 and softmax(g2) (block=64 per node)
// ---------------------------------------------------------------------------
__global__ void k_final(const float* __restrict__ Y2, const int* __restrict__ nbr,
                        const int* __restrict__ cnt, float* __restrict__ out) {
    int n = blockIdx.x;
    int lane = threadIdx.x;            // 0..63
    int c = cnt[n];
    const int* nb = nbr + n * CAP;
    float acc = 0.0f;
    for (int j = 0; j < c; ++j) acc += Y2[(size_t)nb[j] * NH3 + lane];
    out[(size_t)n * NH3 + lane] = acc;
    float mx = acc;
    #pragma unroll
    for (int off = 32; off; off >>= 1) mx = fmaxf(mx, __shfl_xor(mx, off));
    float p = __expf(acc - mx);
    float s = p;
    #pragma unroll
    for (int off = 32; off; off >>= 1) s += __shfl_xor(s, off);
    out[(size_t)NN * NH3 + (size_t)n * NH3 + lane] = p / s;
}

// ---------------------------------------------------------------------------
extern "C" void kernel_launch(void* const* d_in, const int* in_sizes, int n_in,
                              void* d_out, int out_size, void* d_ws, size_t ws_size,
                              hipStream_t stream) {
    const float* x     = (const float*)d_in[0];   // (4096, 512)
    const float* adj   = (const float*)d_in[1];   // (4096, 4096)
    const float* W_att = (const float*)d_in[2];   // (4, 512, 128)
    const float* a     = (const float*)d_in[3];   // (4, 256)
    const float* W1    = (const float*)d_in[4];   // (512, 256)
    const float* W2    = (const float*)d_in[5];   // (256, 64)
    float* out = (float*)d_out;                   // g2 (4096x64) then softmax (4096x64)

    char* p = (char*)d_ws;
    float* Wcat = (float*)p; p += (size_t)FIN * NH * NH1 * 4;        // 1 MB
    float* Whc  = (float*)p; p += (size_t)NN * NH * NH1 * 4;         // 8 MB
    float* s1   = (float*)p; p += (size_t)NH * NN * 4;
    float* s2   = (float*)p; p += (size_t)NH * NN * 4;
    int*   nbr  = (int*)p;   p += (size_t)NN * CAP * 4;              // 1 MB
    int*   cnt  = (int*)p;   p += (size_t)NN * 4;
    float* xr   = (float*)p; p += (size_t)NN * NH * NH1 * 4;         // 8 MB
    float* y1   = (float*)p; p += (size_t)NN * NH2 * 4;              // 4 MB
    float* g1   = (float*)p; p += (size_t)NN * NH2 * 4;              // 4 MB
    float* y2   = (float*)p; p += (size_t)NN * NH3 * 4;              // 1 MB

    // K0: repack weights
    k_repack_watt<<<(FIN * NH * NH1 + 255) / 256, 256, 0, stream>>>(W_att, Wcat);
    // K1: CSR build (4 rows per 256-thread block)
    k_build_csr<<<NN / 4, 256, 0, stream>>>(adj, nbr, cnt);
    // K2: Whc = x @ Wcat   (4096 x 512, K=512)
    k_gemm_f32<<<dim3((NH * NH1) / BN, NN / BM), 256, 0, stream>>>(x, Wcat, Whc, NN, NH * NH1, FIN);
    // K3: scores
    k_scores<<<NN, 256, 0, stream>>>(Whc, a, s1, s2);
    // K4: attention aggregate -> xr
    k_attn<<<NN, 256, 0, stream>>>(Whc, s1, s2, nbr, cnt, xr);
    // K5: y1 = xr @ W1   (4096 x 256, K=512)
    k_gemm_f32<<<dim3(NH2 / BN, NN / BM), 256, 0, stream>>>(xr, W1, y1, NN, NH2, NH * NH1);
    // K6: g1 = relu(nbrsum(y1))
    k_nbr_sum<<<NN, 256, 0, stream>>>(y1, nbr, cnt, g1, NH2, 1);
    // K7: y2 = g1 @ W2   (4096 x 64, K=256)
    k_gemm_f32<<<dim3(NH3 / BN, NN / BM), 256, 0, stream>>>(g1, W2, y2, NN, NH3, NH2);
    // K8: g2 + softmax -> out
    k_final<<<NN, 64, 0, stream>>>(y2, nbr, cnt, out);
}

// Round 2
// 108.884 us; speedup vs baseline: 2.5754x; 2.5754x over previous
//
#include <hip/hip_runtime.h>
#include <hip/hip_bf16.h>

#define NN    4096
#define FIN   512
#define NH1   128
#define NH    4
#define NH2   256
#define NH3   64
#define CAP   64          // max neighbors per row (mean ~17)
#define ALPHA 0.2f

typedef float f32x4 __attribute__((ext_vector_type(4)));
typedef __bf16 bf16x8 __attribute__((ext_vector_type(8)));

__device__ __forceinline__ unsigned short f2bf(float f) {
    union { float f; unsigned u; } x; x.f = f;
    unsigned r = x.u + 0x7fff + ((x.u >> 16) & 1);   // RNE (finite inputs)
    return (unsigned short)(r >> 16);
}

// ---------------------------------------------------------------------------
// Conversions
// ---------------------------------------------------------------------------
__global__ void k_f32_to_bf16(const float* __restrict__ src, ushort* __restrict__ dst, int n) {
    int i = (blockIdx.x * 256 + threadIdx.x) * 4;
    if (i >= n) return;
    float4 v = *reinterpret_cast<const float4*>(src + i);
    ushort4 o;
    o.x = f2bf(v.x); o.y = f2bf(v.y); o.z = f2bf(v.z); o.w = f2bf(v.w);
    *reinterpret_cast<ushort4*>(dst + i) = o;
}

// W_att (h,f,o) -> Wt[col][f] bf16, col = h*128+o   (512 x 512, N x K form)
__global__ void k_cvt_watt(const float* __restrict__ W_att, ushort* __restrict__ Wt) {
    int idx = blockIdx.x * 256 + threadIdx.x;      // col*512 + f
    if (idx >= 512 * 512) return;
    int col = idx >> 9, f = idx & 511;
    int h = col >> 7, o = col & 127;
    Wt[idx] = f2bf(W_att[h * (FIN * NH1) + f * NH1 + o]);
}

// src (R x C) f32 -> dst (C x R) bf16
__global__ void k_cvt_T(const float* __restrict__ src, ushort* __restrict__ dst, int R, int C) {
    int idx = blockIdx.x * 256 + threadIdx.x;      // c*R + r
    if (idx >= R * C) return;
    int c = idx / R, r = idx % R;
    dst[idx] = f2bf(src[(size_t)r * C + c]);
}

// ---------------------------------------------------------------------------
// CSR build: wave per row, ballot-ordered
// ---------------------------------------------------------------------------
__global__ void k_build_csr(const float* __restrict__ adj, int* __restrict__ nbr,
                            int* __restrict__ cnt) {
    int row = blockIdx.x * (blockDim.x / 64) + (threadIdx.x / 64);
    int lane = threadIdx.x & 63;
    if (row >= NN) return;
    const float* arow = adj + (size_t)row * NN;
    int* out = nbr + row * CAP;
    int base = 0;
    for (int c0 = 0; c0 < NN; c0 += 64) {
        float v = arow[c0 + lane];
        bool pred = v > 0.0f;
        unsigned long long m = __ballot(pred);
        if (pred) {
            int pos = base + __popcll(m & ((1ull << lane) - 1ull));
            if (pos < CAP) out[pos] = c0 + lane;
        }
        base += __popcll(m);
    }
    if (lane == 0) cnt[row] = base < CAP ? base : CAP;
}

// ---------------------------------------------------------------------------
// bf16 MFMA GEMM: C[MxN] = A[MxK] @ Bt[NxK]^T ; 64x64 tile, 4 waves
// A,Bt bf16 row-major; C fp32. M,N,K multiples of 64.
// ---------------------------------------------------------------------------
#define GBM 64
#define GBN 64
#define GBK 64
__global__ __launch_bounds__(256) void k_gemm_bf16(const ushort* __restrict__ A,
                                                   const ushort* __restrict__ Bt,
                                                   float* __restrict__ C,
                                                   int M, int N, int K) {
    __shared__ ushort As[GBM * GBK];
    __shared__ ushort Bs[GBN * GBK];
    const int tid = threadIdx.x;
    const int wid = tid >> 6;
    const int lane = tid & 63;
    const int row0 = blockIdx.y * GBM;
    const int col0 = blockIdx.x * GBN;
    const int wr = wid >> 1, wc = wid & 1;

    f32x4 acc[2][2] = {};

    for (int k0 = 0; k0 < K; k0 += GBK) {
        // stage 8KB per operand: 2 x (256 threads x 16B); linear LDS dest,
        // source chunk pre-swizzled by ^(row&7) so swizzled reads are conflict-free
        #pragma unroll
        for (int j = 0; j < 2; ++j) {
            int ci = j * 256 + tid;           // 16B-chunk index
            int r = ci >> 3;                  // tile row (A) / tile col-row (Bt)
            int sc = (ci & 7) ^ (r & 7);      // swizzled source chunk
            const ushort* ga = A + (size_t)(row0 + r) * K + k0 + sc * 8;
            const ushort* gb = Bt + (size_t)(col0 + r) * K + k0 + sc * 8;
            ushort* la = As + (size_t)(j * 256 + wid * 64) * 8;
            ushort* lb = Bs + (size_t)(j * 256 + wid * 64) * 8;
            __builtin_amdgcn_global_load_lds(
                (const __attribute__((address_space(1))) unsigned int*)ga,
                (__attribute__((address_space(3))) unsigned int*)la, 16, 0, 0);
            __builtin_amdgcn_global_load_lds(
                (const __attribute__((address_space(1))) unsigned int*)gb,
                (__attribute__((address_space(3))) unsigned int*)lb, 16, 0, 0);
        }
        __syncthreads();
        #pragma unroll
        for (int kk = 0; kk < 2; ++kk) {
            bf16x8 af[2], bfv[2];
            #pragma unroll
            for (int m = 0; m < 2; ++m) {
                int r = wr * 32 + m * 16 + (lane & 15);
                int kc = kk * 4 + (lane >> 4);
                int off = r * GBK + (((kc ^ (r & 7)) & 7) << 3);
                af[m] = *reinterpret_cast<const bf16x8*>(&As[off]);
            }
            #pragma unroll
            for (int n = 0; n < 2; ++n) {
                int c = wc * 32 + n * 16 + (lane & 15);
                int kc = kk * 4 + (lane >> 4);
                int off = c * GBK + (((kc ^ (c & 7)) & 7) << 3);
                bfv[n] = *reinterpret_cast<const bf16x8*>(&Bs[off]);
            }
            #pragma unroll
            for (int m = 0; m < 2; ++m)
                #pragma unroll
                for (int n = 0; n < 2; ++n)
                    acc[m][n] = __builtin_amdgcn_mfma_f32_16x16x32_bf16(af[m], bfv[n], acc[m][n], 0, 0, 0);
        }
        __syncthreads();
    }
    #pragma unroll
    for (int m = 0; m < 2; ++m)
        #pragma unroll
        for (int n = 0; n < 2; ++n) {
            int col = col0 + wc * 32 + n * 16 + (lane & 15);
            #pragma unroll
            for (int j2 = 0; j2 < 4; ++j2) {
                int row = row0 + wr * 32 + m * 16 + (lane >> 4) * 4 + j2;
                C[(size_t)row * N + col] = acc[m][n][j2];
            }
        }
}

// ---------------------------------------------------------------------------
// attention scores
// ---------------------------------------------------------------------------
__global__ void k_scores(const float* __restrict__ Whc, const float* __restrict__ a,
                         float* __restrict__ s1, float* __restrict__ s2) {
    int n = blockIdx.x;
    int h = threadIdx.x >> 6;
    int lane = threadIdx.x & 63;
    const float* wrow = Whc + (size_t)n * (NH * NH1) + h * NH1;
    const float* a1 = a + h * (2 * NH1);
    const float* a2 = a1 + NH1;
    float v1 = wrow[lane] * a1[lane] + wrow[lane + 64] * a1[lane + 64];
    float v2 = wrow[lane] * a2[lane] + wrow[lane + 64] * a2[lane + 64];
    #pragma unroll
    for (int off = 32; off; off >>= 1) {
        v1 += __shfl_down(v1, off);
        v2 += __shfl_down(v2, off);
    }
    if (lane == 0) {
        s1[h * NN + n] = v1;
        s2[h * NN + n] = v2;
    }
}

// ---------------------------------------------------------------------------
// attention softmax + aggregate + ReLU -> xrb (bf16, N x 512)
// ---------------------------------------------------------------------------
__global__ void k_attn(const float* __restrict__ Whc, const float* __restrict__ s1,
                       const float* __restrict__ s2, const int* __restrict__ nbr,
                       const int* __restrict__ cnt, ushort* __restrict__ xrb) {
    int n = blockIdx.x;
    int h = threadIdx.x >> 6;
    int lane = threadIdx.x & 63;
    int c = cnt[n];
    const int* nb = nbr + n * CAP;
    int m = (lane < c) ? nb[lane] : 0;
    float e = -1e30f;
    float s1n = s1[h * NN + n];
    if (lane < c) {
        float t = s1n + s2[h * NN + m];
        e = (t >= 0.0f) ? t : ALPHA * t;
    }
    float mx = e;
    #pragma unroll
    for (int off = 32; off; off >>= 1) mx = fmaxf(mx, __shfl_xor(mx, off));
    float p = (lane < c) ? __expf(e - mx) : 0.0f;
    float s = p;
    #pragma unroll
    for (int off = 32; off; off >>= 1) s += __shfl_xor(s, off);
    p /= s;
    float acc0 = 0.0f, acc1 = 0.0f;
    for (int j = 0; j < c; ++j) {
        float pj = __shfl(p, j);
        int mj = __shfl(m, j);
        const float* w = Whc + (size_t)mj * (NH * NH1) + h * NH1;
        acc0 = fmaf(pj, w[lane], acc0);
        acc1 = fmaf(pj, w[lane + 64], acc1);
    }
    ushort* outp = xrb + (size_t)n * (NH * NH1) + h * NH1;
    outp[lane]      = f2bf(fmaxf(acc0, 0.0f));
    outp[lane + 64] = f2bf(fmaxf(acc1, 0.0f));
}

// ---------------------------------------------------------------------------
// g1 = relu(nbrsum(y1)) -> bf16
// ---------------------------------------------------------------------------
__global__ void k_nbr_sum_bf(const float* __restrict__ Y, const int* __restrict__ nbr,
                             const int* __restrict__ cnt, ushort* __restrict__ out, int C) {
    int n = blockIdx.x;
    int c = cnt[n];
    const int* nb = nbr + n * CAP;
    for (int col = threadIdx.x; col < C; col += blockDim.x) {
        float acc = 0.0f;
        for (int j = 0; j < c; ++j) acc += Y[(size_t)nb[j] * C + col];
        out[(size_t)n * C + col] = f2bf(fmaxf(acc, 0.0f));
    }
}

// ---------------------------------------------------------------------------
// final: g2 = nbrsum(y2); write g2 and softmax(g2)
// ---------------------------------------------------------------------------
__global__ void k_final(const float* __restrict__ Y2, const int* __restrict__ nbr,
                        const int* __restrict__ cnt, float* __restrict__ out) {
    int n = blockIdx.x;
    int lane = threadIdx.x;            // 0..63
    int c = cnt[n];
    const int* nb = nbr + n * CAP;
    float acc = 0.0f;
    for (int j = 0; j < c; ++j) acc += Y2[(size_t)nb[j] * NH3 + lane];
    out[(size_t)n * NH3 + lane] = acc;
    float mx = acc;
    #pragma unroll
    for (int off = 32; off; off >>= 1) mx = fmaxf(mx, __shfl_xor(mx, off));
    float p = __expf(acc - mx);
    float s = p;
    #pragma unroll
    for (int off = 32; off; off >>= 1) s += __shfl_xor(s, off);
    out[(size_t)NN * NH3 + (size_t)n * NH3 + lane] = p / s;
}

// ---------------------------------------------------------------------------
extern "C" void kernel_launch(void* const* d_in, const int* in_sizes, int n_in,
                              void* d_out, int out_size, void* d_ws, size_t ws_size,
                              hipStream_t stream) {
    const float* x     = (const float*)d_in[0];   // (4096, 512)
    const float* adj   = (const float*)d_in[1];   // (4096, 4096)
    const float* W_att = (const float*)d_in[2];   // (4, 512, 128)
    const float* a     = (const float*)d_in[3];   // (4, 256)
    const float* W1    = (const float*)d_in[4];   // (512, 256)
    const float* W2    = (const float*)d_in[5];   // (256, 64)
    float* out = (float*)d_out;

    char* p = (char*)d_ws;
    ushort* xb    = (ushort*)p; p += (size_t)NN * FIN * 2;           // 4 MB
    ushort* Wattb = (ushort*)p; p += (size_t)FIN * NH * NH1 * 2;     // 0.5 MB
    ushort* W1t   = (ushort*)p; p += (size_t)NH2 * (NH * NH1) * 2;   // 0.25 MB
    ushort* W2t   = (ushort*)p; p += (size_t)NH3 * NH2 * 2;          // 32 KB
    float*  Whc   = (float*)p;  p += (size_t)NN * NH * NH1 * 4;      // 8 MB
    float*  s1    = (float*)p;  p += (size_t)NH * NN * 4;
    float*  s2    = (float*)p;  p += (size_t)NH * NN * 4;
    int*    nbr   = (int*)p;    p += (size_t)NN * CAP * 4;           // 1 MB
    int*    cnt   = (int*)p;    p += (size_t)NN * 4;
    ushort* xrb   = (ushort*)p; p += (size_t)NN * NH * NH1 * 2;      // 4 MB
    float*  y1    = (float*)p;  p += (size_t)NN * NH2 * 4;           // 4 MB
    ushort* g1b   = (ushort*)p; p += (size_t)NN * NH2 * 2;           // 2 MB
    float*  y2    = (float*)p;  p += (size_t)NN * NH3 * 4;           // 1 MB

    // conversions
    k_f32_to_bf16<<<(NN * FIN / 4 + 255) / 256, 256, 0, stream>>>(x, xb, NN * FIN);
    k_cvt_watt<<<(512 * 512 + 255) / 256, 256, 0, stream>>>(W_att, Wattb);
    k_cvt_T<<<(512 * 256 + 255) / 256, 256, 0, stream>>>(W1, W1t, NH * NH1, NH2);
    k_cvt_T<<<(256 * 64 + 255) / 256, 256, 0, stream>>>(W2, W2t, NH2, NH3);
    // CSR
    k_build_csr<<<NN / 4, 256, 0, stream>>>(adj, nbr, cnt);
    // Whc = x @ Wcat  (4096 x 512, K=512)
    k_gemm_bf16<<<dim3((NH * NH1) / GBN, NN / GBM), 256, 0, stream>>>(xb, Wattb, Whc, NN, NH * NH1, FIN);
    // scores
    k_scores<<<NN, 256, 0, stream>>>(Whc, a, s1, s2);
    // attention -> xrb (bf16)
    k_attn<<<NN, 256, 0, stream>>>(Whc, s1, s2, nbr, cnt, xrb);
    // y1 = xr @ W1  (4096 x 256, K=512)
    k_gemm_bf16<<<dim3(NH2 / GBN, NN / GBM), 256, 0, stream>>>(xrb, W1t, y1, NN, NH2, NH * NH1);
    // g1 = relu(nbrsum(y1)) -> bf16
    k_nbr_sum_bf<<<NN, 256, 0, stream>>>(y1, nbr, cnt, g1b, NH2);
    // y2 = g1 @ W2  (4096 x 64, K=256)
    k_gemm_bf16<<<dim3(NH3 / GBN, NN / GBM), 256, 0, stream>>>(g1b, W2t, y2, NN, NH3, NH2);
    // g2 + softmax
    k_final<<<NN, 64, 0, stream>>>(y2, nbr, cnt, out);
}

// Round 3
// 102.970 us; speedup vs baseline: 2.7234x; 1.0574x over previous
//
#include <hip/hip_runtime.h>
#include <hip/hip_bf16.h>

#define NN    4096
#define FIN   512
#define NH1   128
#define NH    4
#define NH2   256
#define NH3   64
#define CAP   64          // max neighbors per row (mean ~17)
#define ALPHA 0.2f

typedef float f32x4 __attribute__((ext_vector_type(4)));
typedef __bf16 bf16x8 __attribute__((ext_vector_type(8)));

__device__ __forceinline__ unsigned short f2bf(float f) {
    union { float f; unsigned u; } x; x.f = f;
    unsigned r = x.u + 0x7fff + ((x.u >> 16) & 1);   // RNE (finite inputs)
    return (unsigned short)(r >> 16);
}

// ---------------------------------------------------------------------------
// Conversions
// ---------------------------------------------------------------------------
__global__ void k_f32_to_bf16(const float* __restrict__ src, ushort* __restrict__ dst, int n) {
    int i = (blockIdx.x * 256 + threadIdx.x) * 4;
    if (i >= n) return;
    float4 v = *reinterpret_cast<const float4*>(src + i);
    ushort4 o;
    o.x = f2bf(v.x); o.y = f2bf(v.y); o.z = f2bf(v.z); o.w = f2bf(v.w);
    *reinterpret_cast<ushort4*>(dst + i) = o;
}

// W_att (h,f,o) -> Wt[col][f] bf16, col = h*128+o   (512 x 512, N x K form)
__global__ void k_cvt_watt(const float* __restrict__ W_att, ushort* __restrict__ Wt) {
    int idx = blockIdx.x * 256 + threadIdx.x;      // col*512 + f
    if (idx >= 512 * 512) return;
    int col = idx >> 9, f = idx & 511;
    int h = col >> 7, o = col & 127;
    Wt[idx] = f2bf(W_att[h * (FIN * NH1) + f * NH1 + o]);
}

// src (R x C) f32 -> dst (C x R) bf16
__global__ void k_cvt_T(const float* __restrict__ src, ushort* __restrict__ dst, int R, int C) {
    int idx = blockIdx.x * 256 + threadIdx.x;      // c*R + r
    if (idx >= R * C) return;
    int c = idx / R, r = idx % R;
    dst[idx] = f2bf(src[(size_t)r * C + c]);
}

// ---------------------------------------------------------------------------
// CSR build: wave per row; uint4 loads, all 16 issued up front (1 round trip)
// adj values are exactly 0.0f or 1.0f -> integer !=0 test on raw bits
// ---------------------------------------------------------------------------
__global__ __launch_bounds__(256) void k_build_csr(const float* __restrict__ adj,
                                                   int* __restrict__ nbr,
                                                   int* __restrict__ cnt) {
    int row = blockIdx.x * 4 + (threadIdx.x >> 6);
    int lane = threadIdx.x & 63;
    const uint4* arow = (const uint4*)(adj + (size_t)row * NN);
    int* out = nbr + row * CAP;

    uint4 v[16];
    #pragma unroll
    for (int it = 0; it < 16; ++it) v[it] = arow[it * 64 + lane];

    const unsigned long long below = (1ull << lane) - 1ull;
    int base = 0;
    #pragma unroll
    for (int it = 0; it < 16; ++it) {
        unsigned long long b0 = __ballot(v[it].x != 0u);
        unsigned long long b1 = __ballot(v[it].y != 0u);
        unsigned long long b2 = __ballot(v[it].z != 0u);
        unsigned long long b3 = __ballot(v[it].w != 0u);
        int pre = __popcll(b0 & below) + __popcll(b1 & below) +
                  __popcll(b2 & below) + __popcll(b3 & below);
        int col0 = it * 256 + lane * 4;
        int pos = base + pre;
        if (v[it].x != 0u) { if (pos < CAP) out[pos] = col0;     ++pos; }
        if (v[it].y != 0u) { if (pos < CAP) out[pos] = col0 + 1; ++pos; }
        if (v[it].z != 0u) { if (pos < CAP) out[pos] = col0 + 2; ++pos; }
        if (v[it].w != 0u) { if (pos < CAP) out[pos] = col0 + 3; ++pos; }
        base += __popcll(b0) + __popcll(b1) + __popcll(b2) + __popcll(b3);
    }
    if (lane == 0) cnt[row] = base < CAP ? base : CAP;
}

// ---------------------------------------------------------------------------
// bf16 MFMA GEMM: C[MxN] = A[MxK] @ Bt[NxK]^T ; 64x64 tile, 4 waves
// ---------------------------------------------------------------------------
#define GBM 64
#define GBN 64
#define GBK 64
__global__ __launch_bounds__(256) void k_gemm_bf16(const ushort* __restrict__ A,
                                                   const ushort* __restrict__ Bt,
                                                   float* __restrict__ C,
                                                   int M, int N, int K) {
    __shared__ ushort As[GBM * GBK];
    __shared__ ushort Bs[GBN * GBK];
    const int tid = threadIdx.x;
    const int wid = tid >> 6;
    const int lane = tid & 63;
    const int row0 = blockIdx.y * GBM;
    const int col0 = blockIdx.x * GBN;
    const int wr = wid >> 1, wc = wid & 1;

    f32x4 acc[2][2] = {};

    for (int k0 = 0; k0 < K; k0 += GBK) {
        #pragma unroll
        for (int j = 0; j < 2; ++j) {
            int ci = j * 256 + tid;           // 16B-chunk index
            int r = ci >> 3;
            int sc = (ci & 7) ^ (r & 7);      // pre-swizzled source chunk
            const ushort* ga = A + (size_t)(row0 + r) * K + k0 + sc * 8;
            const ushort* gb = Bt + (size_t)(col0 + r) * K + k0 + sc * 8;
            ushort* la = As + (size_t)(j * 256 + wid * 64) * 8;
            ushort* lb = Bs + (size_t)(j * 256 + wid * 64) * 8;
            __builtin_amdgcn_global_load_lds(
                (const __attribute__((address_space(1))) unsigned int*)ga,
                (__attribute__((address_space(3))) unsigned int*)la, 16, 0, 0);
            __builtin_amdgcn_global_load_lds(
                (const __attribute__((address_space(1))) unsigned int*)gb,
                (__attribute__((address_space(3))) unsigned int*)lb, 16, 0, 0);
        }
        __syncthreads();
        #pragma unroll
        for (int kk = 0; kk < 2; ++kk) {
            bf16x8 af[2], bfv[2];
            #pragma unroll
            for (int m = 0; m < 2; ++m) {
                int r = wr * 32 + m * 16 + (lane & 15);
                int kc = kk * 4 + (lane >> 4);
                int off = r * GBK + (((kc ^ (r & 7)) & 7) << 3);
                af[m] = *reinterpret_cast<const bf16x8*>(&As[off]);
            }
            #pragma unroll
            for (int n = 0; n < 2; ++n) {
                int c = wc * 32 + n * 16 + (lane & 15);
                int kc = kk * 4 + (lane >> 4);
                int off = c * GBK + (((kc ^ (c & 7)) & 7) << 3);
                bfv[n] = *reinterpret_cast<const bf16x8*>(&Bs[off]);
            }
            #pragma unroll
            for (int m = 0; m < 2; ++m)
                #pragma unroll
                for (int n = 0; n < 2; ++n)
                    acc[m][n] = __builtin_amdgcn_mfma_f32_16x16x32_bf16(af[m], bfv[n], acc[m][n], 0, 0, 0);
        }
        __syncthreads();
    }
    #pragma unroll
    for (int m = 0; m < 2; ++m)
        #pragma unroll
        for (int n = 0; n < 2; ++n) {
            int col = col0 + wc * 32 + n * 16 + (lane & 15);
            #pragma unroll
            for (int j2 = 0; j2 < 4; ++j2) {
                int row = row0 + wr * 32 + m * 16 + (lane >> 4) * 4 + j2;
                C[(size_t)row * N + col] = acc[m][n][j2];
            }
        }
}

// ---------------------------------------------------------------------------
// attention scores
// ---------------------------------------------------------------------------
__global__ void k_scores(const float* __restrict__ Whc, const float* __restrict__ a,
                         float* __restrict__ s1, float* __restrict__ s2) {
    int n = blockIdx.x;
    int h = threadIdx.x >> 6;
    int lane = threadIdx.x & 63;
    const float* wrow = Whc + (size_t)n * (NH * NH1) + h * NH1;
    const float* a1 = a + h * (2 * NH1);
    const float* a2 = a1 + NH1;
    float v1 = wrow[lane] * a1[lane] + wrow[lane + 64] * a1[lane + 64];
    float v2 = wrow[lane] * a2[lane] + wrow[lane + 64] * a2[lane + 64];
    #pragma unroll
    for (int off = 32; off; off >>= 1) {
        v1 += __shfl_down(v1, off);
        v2 += __shfl_down(v2, off);
    }
    if (lane == 0) {
        s1[h * NN + n] = v1;
        s2[h * NN + n] = v2;
    }
}

// ---------------------------------------------------------------------------
// attention softmax + aggregate + ReLU -> xrb (bf16, N x 512)
// ---------------------------------------------------------------------------
__global__ void k_attn(const float* __restrict__ Whc, const float* __restrict__ s1,
                       const float* __restrict__ s2, const int* __restrict__ nbr,
                       const int* __restrict__ cnt, ushort* __restrict__ xrb) {
    int n = blockIdx.x;
    int h = threadIdx.x >> 6;
    int lane = threadIdx.x & 63;
    int c = cnt[n];
    const int* nb = nbr + n * CAP;
    int m = (lane < c) ? nb[lane] : 0;
    float e = -1e30f;
    float s1n = s1[h * NN + n];
    if (lane < c) {
        float t = s1n + s2[h * NN + m];
        e = (t >= 0.0f) ? t : ALPHA * t;
    }
    float mx = e;
    #pragma unroll
    for (int off = 32; off; off >>= 1) mx = fmaxf(mx, __shfl_xor(mx, off));
    float p = (lane < c) ? __expf(e - mx) : 0.0f;
    float s = p;
    #pragma unroll
    for (int off = 32; off; off >>= 1) s += __shfl_xor(s, off);
    p /= s;
    float acc0 = 0.0f, acc1 = 0.0f;
    for (int j = 0; j < c; ++j) {
        float pj = __shfl(p, j);
        int mj = __shfl(m, j);
        const float* w = Whc + (size_t)mj * (NH * NH1) + h * NH1;
        acc0 = fmaf(pj, w[lane], acc0);
        acc1 = fmaf(pj, w[lane + 64], acc1);
    }
    ushort* outp = xrb + (size_t)n * (NH * NH1) + h * NH1;
    outp[lane]      = f2bf(fmaxf(acc0, 0.0f));
    outp[lane + 64] = f2bf(fmaxf(acc1, 0.0f));
}

// ---------------------------------------------------------------------------
// g1 = relu(nbrsum(y1)) -> bf16
// ---------------------------------------------------------------------------
__global__ void k_nbr_sum_bf(const float* __restrict__ Y, const int* __restrict__ nbr,
                             const int* __restrict__ cnt, ushort* __restrict__ out, int C) {
    int n = blockIdx.x;
    int c = cnt[n];
    const int* nb = nbr + n * CAP;
    for (int col = threadIdx.x; col < C; col += blockDim.x) {
        float acc = 0.0f;
        for (int j = 0; j < c; ++j) acc += Y[(size_t)nb[j] * C + col];
        out[(size_t)n * C + col] = f2bf(fmaxf(acc, 0.0f));
    }
}

// ---------------------------------------------------------------------------
// final: g2 = nbrsum(y2); write g2 and softmax(g2)
// ---------------------------------------------------------------------------
__global__ void k_final(const float* __restrict__ Y2, const int* __restrict__ nbr,
                        const int* __restrict__ cnt, float* __restrict__ out) {
    int n = blockIdx.x;
    int lane = threadIdx.x;            // 0..63
    int c = cnt[n];
    const int* nb = nbr + n * CAP;
    float acc = 0.0f;
    for (int j = 0; j < c; ++j) acc += Y2[(size_t)nb[j] * NH3 + lane];
    out[(size_t)n * NH3 + lane] = acc;
    float mx = acc;
    #pragma unroll
    for (int off = 32; off; off >>= 1) mx = fmaxf(mx, __shfl_xor(mx, off));
    float p = __expf(acc - mx);
    float s = p;
    #pragma unroll
    for (int off = 32; off; off >>= 1) s += __shfl_xor(s, off);
    out[(size_t)NN * NH3 + (size_t)n * NH3 + lane] = p / s;
}

// ---------------------------------------------------------------------------
extern "C" void kernel_launch(void* const* d_in, const int* in_sizes, int n_in,
                              void* d_out, int out_size, void* d_ws, size_t ws_size,
                              hipStream_t stream) {
    const float* x     = (const float*)d_in[0];   // (4096, 512)
    const float* adj   = (const float*)d_in[1];   // (4096, 4096)
    const float* W_att = (const float*)d_in[2];   // (4, 512, 128)
    const float* a     = (const float*)d_in[3];   // (4, 256)
    const float* W1    = (const float*)d_in[4];   // (512, 256)
    const float* W2    = (const float*)d_in[5];   // (256, 64)
    float* out = (float*)d_out;

    char* p = (char*)d_ws;
    ushort* xb    = (ushort*)p; p += (size_t)NN * FIN * 2;           // 4 MB
    ushort* Wattb = (ushort*)p; p += (size_t)FIN * NH * NH1 * 2;     // 0.5 MB
    ushort* W1t   = (ushort*)p; p += (size_t)NH2 * (NH * NH1) * 2;   // 0.25 MB
    ushort* W2t   = (ushort*)p; p += (size_t)NH3 * NH2 * 2;          // 32 KB
    float*  Whc   = (float*)p;  p += (size_t)NN * NH * NH1 * 4;      // 8 MB
    float*  s1    = (float*)p;  p += (size_t)NH * NN * 4;
    float*  s2    = (float*)p;  p += (size_t)NH * NN * 4;
    int*    nbr   = (int*)p;    p += (size_t)NN * CAP * 4;           // 1 MB
    int*    cnt   = (int*)p;    p += (size_t)NN * 4;
    ushort* xrb   = (ushort*)p; p += (size_t)NN * NH * NH1 * 2;      // 4 MB
    float*  y1    = (float*)p;  p += (size_t)NN * NH2 * 4;           // 4 MB
    ushort* g1b   = (ushort*)p; p += (size_t)NN * NH2 * 2;           // 2 MB
    float*  y2    = (float*)p;  p += (size_t)NN * NH3 * 4;           // 1 MB

    // conversions
    k_f32_to_bf16<<<(NN * FIN / 4 + 255) / 256, 256, 0, stream>>>(x, xb, NN * FIN);
    k_cvt_watt<<<(512 * 512 + 255) / 256, 256, 0, stream>>>(W_att, Wattb);
    k_cvt_T<<<(512 * 256 + 255) / 256, 256, 0, stream>>>(W1, W1t, NH * NH1, NH2);
    k_cvt_T<<<(256 * 64 + 255) / 256, 256, 0, stream>>>(W2, W2t, NH2, NH3);
    // CSR
    k_build_csr<<<NN / 4, 256, 0, stream>>>(adj, nbr, cnt);
    // Whc = x @ Wcat  (4096 x 512, K=512)
    k_gemm_bf16<<<dim3((NH * NH1) / GBN, NN / GBM), 256, 0, stream>>>(xb, Wattb, Whc, NN, NH * NH1, FIN);
    // scores
    k_scores<<<NN, 256, 0, stream>>>(Whc, a, s1, s2);
    // attention -> xrb (bf16)
    k_attn<<<NN, 256, 0, stream>>>(Whc, s1, s2, nbr, cnt, xrb);
    // y1 = xr @ W1  (4096 x 256, K=512)
    k_gemm_bf16<<<dim3(NH2 / GBN, NN / GBM), 256, 0, stream>>>(xrb, W1t, y1, NN, NH2, NH * NH1);
    // g1 = relu(nbrsum(y1)) -> bf16
    k_nbr_sum_bf<<<NN, 256, 0, stream>>>(y1, nbr, cnt, g1b, NH2);
    // y2 = g1 @ W2  (4096 x 64, K=256)
    k_gemm_bf16<<<dim3(NH3 / GBN, NN / GBM), 256, 0, stream>>>(g1b, W2t, y2, NN, NH3, NH2);
    // g2 + softmax
    k_final<<<NN, 64, 0, stream>>>(y2, nbr, cnt, out);
}

// Round 4
// 99.588 us; speedup vs baseline: 2.8159x; 1.0340x over previous
//
#include <hip/hip_runtime.h>
#include <hip/hip_bf16.h>

#define NN    4096
#define FIN   512
#define NH1   128
#define NH    4
#define NH2   256
#define NH3   64
#define CAP   64          // max neighbors per row (mean ~17)
#define ALPHA 0.2f

typedef float f32x4 __attribute__((ext_vector_type(4)));
typedef __bf16 bf16x8 __attribute__((ext_vector_type(8)));

__device__ __forceinline__ unsigned short f2bf(float f) {
    union { float f; unsigned u; } x; x.f = f;
    unsigned r = x.u + 0x7fff + ((x.u >> 16) & 1);   // RNE (finite inputs)
    return (unsigned short)(r >> 16);
}
__device__ __forceinline__ float bf2f(ushort u) {
    union { unsigned u; float f; } x; x.u = ((unsigned)u) << 16;
    return x.f;
}

// ---------------------------------------------------------------------------
// Conversions
// ---------------------------------------------------------------------------
__global__ void k_f32_to_bf16(const float* __restrict__ src, ushort* __restrict__ dst, int n) {
    int i = (blockIdx.x * 256 + threadIdx.x) * 4;
    if (i >= n) return;
    float4 v = *reinterpret_cast<const float4*>(src + i);
    ushort4 o;
    o.x = f2bf(v.x); o.y = f2bf(v.y); o.z = f2bf(v.z); o.w = f2bf(v.w);
    *reinterpret_cast<ushort4*>(dst + i) = o;
}

// W_att (h,f,o) -> Wt[col][f] bf16, col = h*128+o   (512 x 512, N x K form)
__global__ void k_cvt_watt(const float* __restrict__ W_att, ushort* __restrict__ Wt) {
    int idx = blockIdx.x * 256 + threadIdx.x;      // col*512 + f
    if (idx >= 512 * 512) return;
    int col = idx >> 9, f = idx & 511;
    int h = col >> 7, o = col & 127;
    Wt[idx] = f2bf(W_att[h * (FIN * NH1) + f * NH1 + o]);
}

// src (R x C) f32 -> dst (C x R) bf16
__global__ void k_cvt_T(const float* __restrict__ src, ushort* __restrict__ dst, int R, int C) {
    int idx = blockIdx.x * 256 + threadIdx.x;      // c*R + r
    if (idx >= R * C) return;
    int c = idx / R, r = idx % R;
    dst[idx] = f2bf(src[(size_t)r * C + c]);
}

// ---------------------------------------------------------------------------
// CSR build: one block (4 waves) per row. Each wave scans a 1024-col quarter
// with 4 upfront uint4 loads (one round-trip), ballot-compacts to LDS, then
// cross-wave prefix merge. adj values are exactly 0.0/1.0 -> int !=0 test.
// ---------------------------------------------------------------------------
__global__ __launch_bounds__(256) void k_build_csr(const float* __restrict__ adj,
                                                   int* __restrict__ nbr,
                                                   int* __restrict__ cnt) {
    __shared__ int lds_list[4][64];
    __shared__ int lds_cnt[4];
    int row = blockIdx.x;
    int wid = threadIdx.x >> 6;
    int lane = threadIdx.x & 63;
    const uint4* arow = (const uint4*)(adj + (size_t)row * NN);

    uint4 v[4];
    #pragma unroll
    for (int it = 0; it < 4; ++it) v[it] = arow[wid * 256 + it * 64 + lane];

    const unsigned long long below = (1ull << lane) - 1ull;
    int base = 0;
    #pragma unroll
    for (int it = 0; it < 4; ++it) {
        unsigned long long b0 = __ballot(v[it].x != 0u);
        unsigned long long b1 = __ballot(v[it].y != 0u);
        unsigned long long b2 = __ballot(v[it].z != 0u);
        unsigned long long b3 = __ballot(v[it].w != 0u);
        int pre = __popcll(b0 & below) + __popcll(b1 & below) +
                  __popcll(b2 & below) + __popcll(b3 & below);
        int col0 = wid * 1024 + it * 256 + lane * 4;
        int pos = base + pre;
        if (v[it].x != 0u) { if (pos < 64) lds_list[wid][pos] = col0;     ++pos; }
        if (v[it].y != 0u) { if (pos < 64) lds_list[wid][pos] = col0 + 1; ++pos; }
        if (v[it].z != 0u) { if (pos < 64) lds_list[wid][pos] = col0 + 2; ++pos; }
        if (v[it].w != 0u) { if (pos < 64) lds_list[wid][pos] = col0 + 3; ++pos; }
        base += __popcll(b0) + __popcll(b1) + __popcll(b2) + __popcll(b3);
    }
    if (lane == 0) lds_cnt[wid] = base;
    __syncthreads();
    int c0 = lds_cnt[0], c1 = lds_cnt[1], c2 = lds_cnt[2], c3 = lds_cnt[3];
    int off = (wid > 0 ? c0 : 0) + (wid > 1 ? c1 : 0) + (wid > 2 ? c2 : 0);
    int my = lds_cnt[wid]; if (my > 64) my = 64;
    int* outp = nbr + row * CAP;
    if (lane < my) {
        int gpos = off + lane;
        if (gpos < CAP) outp[gpos] = lds_list[wid][lane];
    }
    if (threadIdx.x == 0) {
        int tot = c0 + c1 + c2 + c3;
        cnt[row] = tot < CAP ? tot : CAP;
    }
}

// ---------------------------------------------------------------------------
// bf16 MFMA GEMM: C[MxN] = A[MxK] @ Bt[NxK]^T ; 64x64 tile, 4 waves
// OM: 0 = f32 out, 1 = bf16 out, 2 = both
// ---------------------------------------------------------------------------
#define GBM 64
#define GBN 64
#define GBK 64
template <int OM>
__global__ __launch_bounds__(256) void k_gemm_bf16(const ushort* __restrict__ A,
                                                   const ushort* __restrict__ Bt,
                                                   float* __restrict__ C,
                                                   ushort* __restrict__ Cb,
                                                   int M, int N, int K) {
    __shared__ ushort As[GBM * GBK];
    __shared__ ushort Bs[GBN * GBK];
    const int tid = threadIdx.x;
    const int wid = tid >> 6;
    const int lane = tid & 63;
    const int row0 = blockIdx.y * GBM;
    const int col0 = blockIdx.x * GBN;
    const int wr = wid >> 1, wc = wid & 1;

    f32x4 acc[2][2] = {};

    for (int k0 = 0; k0 < K; k0 += GBK) {
        #pragma unroll
        for (int j = 0; j < 2; ++j) {
            int ci = j * 256 + tid;           // 16B-chunk index
            int r = ci >> 3;
            int sc = (ci & 7) ^ (r & 7);      // pre-swizzled source chunk
            const ushort* ga = A + (size_t)(row0 + r) * K + k0 + sc * 8;
            const ushort* gb = Bt + (size_t)(col0 + r) * K + k0 + sc * 8;
            ushort* la = As + (size_t)(j * 256 + wid * 64) * 8;
            ushort* lb = Bs + (size_t)(j * 256 + wid * 64) * 8;
            __builtin_amdgcn_global_load_lds(
                (const __attribute__((address_space(1))) unsigned int*)ga,
                (__attribute__((address_space(3))) unsigned int*)la, 16, 0, 0);
            __builtin_amdgcn_global_load_lds(
                (const __attribute__((address_space(1))) unsigned int*)gb,
                (__attribute__((address_space(3))) unsigned int*)lb, 16, 0, 0);
        }
        __syncthreads();
        #pragma unroll
        for (int kk = 0; kk < 2; ++kk) {
            bf16x8 af[2], bfv[2];
            #pragma unroll
            for (int m = 0; m < 2; ++m) {
                int r = wr * 32 + m * 16 + (lane & 15);
                int kc = kk * 4 + (lane >> 4);
                int off = r * GBK + (((kc ^ (r & 7)) & 7) << 3);
                af[m] = *reinterpret_cast<const bf16x8*>(&As[off]);
            }
            #pragma unroll
            for (int n = 0; n < 2; ++n) {
                int c = wc * 32 + n * 16 + (lane & 15);
                int kc = kk * 4 + (lane >> 4);
                int off = c * GBK + (((kc ^ (c & 7)) & 7) << 3);
                bfv[n] = *reinterpret_cast<const bf16x8*>(&Bs[off]);
            }
            #pragma unroll
            for (int m = 0; m < 2; ++m)
                #pragma unroll
                for (int n = 0; n < 2; ++n)
                    acc[m][n] = __builtin_amdgcn_mfma_f32_16x16x32_bf16(af[m], bfv[n], acc[m][n], 0, 0, 0);
        }
        __syncthreads();
    }
    #pragma unroll
    for (int m = 0; m < 2; ++m)
        #pragma unroll
        for (int n = 0; n < 2; ++n) {
            int col = col0 + wc * 32 + n * 16 + (lane & 15);
            #pragma unroll
            for (int j2 = 0; j2 < 4; ++j2) {
                int row = row0 + wr * 32 + m * 16 + (lane >> 4) * 4 + j2;
                float val = acc[m][n][j2];
                if (OM == 0 || OM == 2) C[(size_t)row * N + col] = val;
                if (OM == 1 || OM == 2) Cb[(size_t)row * N + col] = f2bf(val);
            }
        }
}

// ---------------------------------------------------------------------------
// attention scores (from fp32 Whc)
// ---------------------------------------------------------------------------
__global__ void k_scores(const float* __restrict__ Whc, const float* __restrict__ a,
                         float* __restrict__ s1, float* __restrict__ s2) {
    int n = blockIdx.x;
    int h = threadIdx.x >> 6;
    int lane = threadIdx.x & 63;
    const float* wrow = Whc + (size_t)n * (NH * NH1) + h * NH1;
    const float* a1 = a + h * (2 * NH1);
    const float* a2 = a1 + NH1;
    float v1 = wrow[lane] * a1[lane] + wrow[lane + 64] * a1[lane + 64];
    float v2 = wrow[lane] * a2[lane] + wrow[lane + 64] * a2[lane + 64];
    #pragma unroll
    for (int off = 32; off; off >>= 1) {
        v1 += __shfl_down(v1, off);
        v2 += __shfl_down(v2, off);
    }
    if (lane == 0) {
        s1[h * NN + n] = v1;
        s2[h * NN + n] = v2;
    }
}

// ---------------------------------------------------------------------------
// attention softmax + aggregate (bf16 Wh gather) + ReLU -> xrb (bf16)
// ---------------------------------------------------------------------------
__global__ void k_attn(const ushort* __restrict__ Whb, const float* __restrict__ s1,
                       const float* __restrict__ s2, const int* __restrict__ nbr,
                       const int* __restrict__ cnt, ushort* __restrict__ xrb) {
    int n = blockIdx.x;
    int h = threadIdx.x >> 6;
    int lane = threadIdx.x & 63;
    int c = cnt[n];
    const int* nb = nbr + n * CAP;
    int m = (lane < c) ? nb[lane] : 0;
    float e = -1e30f;
    float s1n = s1[h * NN + n];
    if (lane < c) {
        float t = s1n + s2[h * NN + m];
        e = (t >= 0.0f) ? t : ALPHA * t;
    }
    float mx = e;
    #pragma unroll
    for (int off = 32; off; off >>= 1) mx = fmaxf(mx, __shfl_xor(mx, off));
    float p = (lane < c) ? __expf(e - mx) : 0.0f;
    float s = p;
    #pragma unroll
    for (int off = 32; off; off >>= 1) s += __shfl_xor(s, off);
    p /= s;
    float acc0 = 0.0f, acc1 = 0.0f;
    for (int j = 0; j < c; ++j) {
        float pj = __shfl(p, j);
        int mj = __shfl(m, j);
        const ushort* w = Whb + (size_t)mj * (NH * NH1) + h * NH1;
        acc0 = fmaf(pj, bf2f(w[lane]), acc0);
        acc1 = fmaf(pj, bf2f(w[lane + 64]), acc1);
    }
    ushort* outp = xrb + (size_t)n * (NH * NH1) + h * NH1;
    outp[lane]      = f2bf(fmaxf(acc0, 0.0f));
    outp[lane + 64] = f2bf(fmaxf(acc1, 0.0f));
}

// ---------------------------------------------------------------------------
// g1 = relu(nbrsum(y1b)) -> bf16   (y1b gathered as bf16)
// ---------------------------------------------------------------------------
__global__ void k_nbr_sum_bf(const ushort* __restrict__ Y, const int* __restrict__ nbr,
                             const int* __restrict__ cnt, ushort* __restrict__ out, int C) {
    int n = blockIdx.x;
    int c = cnt[n];
    const int* nb = nbr + n * CAP;
    for (int col = threadIdx.x; col < C; col += blockDim.x) {
        float acc = 0.0f;
        for (int j = 0; j < c; ++j) acc += bf2f(Y[(size_t)nb[j] * C + col]);
        out[(size_t)n * C + col] = f2bf(fmaxf(acc, 0.0f));
    }
}

// ---------------------------------------------------------------------------
// final: g2 = nbrsum(y2); write g2 and softmax(g2)
// ---------------------------------------------------------------------------
__global__ void k_final(const float* __restrict__ Y2, const int* __restrict__ nbr,
                        const int* __restrict__ cnt, float* __restrict__ out) {
    int n = blockIdx.x;
    int lane = threadIdx.x;            // 0..63
    int c = cnt[n];
    const int* nb = nbr + n * CAP;
    float acc = 0.0f;
    for (int j = 0; j < c; ++j) acc += Y2[(size_t)nb[j] * NH3 + lane];
    out[(size_t)n * NH3 + lane] = acc;
    float mx = acc;
    #pragma unroll
    for (int off = 32; off; off >>= 1) mx = fmaxf(mx, __shfl_xor(mx, off));
    float p = __expf(acc - mx);
    float s = p;
    #pragma unroll
    for (int off = 32; off; off >>= 1) s += __shfl_xor(s, off);
    out[(size_t)NN * NH3 + (size_t)n * NH3 + lane] = p / s;
}

// ---------------------------------------------------------------------------
extern "C" void kernel_launch(void* const* d_in, const int* in_sizes, int n_in,
                              void* d_out, int out_size, void* d_ws, size_t ws_size,
                              hipStream_t stream) {
    const float* x     = (const float*)d_in[0];   // (4096, 512)
    const float* adj   = (const float*)d_in[1];   // (4096, 4096)
    const float* W_att = (const float*)d_in[2];   // (4, 512, 128)
    const float* a     = (const float*)d_in[3];   // (4, 256)
    const float* W1    = (const float*)d_in[4];   // (512, 256)
    const float* W2    = (const float*)d_in[5];   // (256, 64)
    float* out = (float*)d_out;

    char* p = (char*)d_ws;
    ushort* xb    = (ushort*)p; p += (size_t)NN * FIN * 2;           // 4 MB
    ushort* Wattb = (ushort*)p; p += (size_t)FIN * NH * NH1 * 2;     // 0.5 MB
    ushort* W1t   = (ushort*)p; p += (size_t)NH2 * (NH * NH1) * 2;   // 0.25 MB
    ushort* W2t   = (ushort*)p; p += (size_t)NH3 * NH2 * 2;          // 32 KB
    float*  Whc   = (float*)p;  p += (size_t)NN * NH * NH1 * 4;      // 8 MB
    ushort* Whb   = (ushort*)p; p += (size_t)NN * NH * NH1 * 2;      // 4 MB
    float*  s1    = (float*)p;  p += (size_t)NH * NN * 4;
    float*  s2    = (float*)p;  p += (size_t)NH * NN * 4;
    int*    nbr   = (int*)p;    p += (size_t)NN * CAP * 4;           // 1 MB
    int*    cnt   = (int*)p;    p += (size_t)NN * 4;
    ushort* xrb   = (ushort*)p; p += (size_t)NN * NH * NH1 * 2;      // 4 MB
    ushort* y1b   = (ushort*)p; p += (size_t)NN * NH2 * 2;           // 2 MB
    ushort* g1b   = (ushort*)p; p += (size_t)NN * NH2 * 2;           // 2 MB
    float*  y2    = (float*)p;  p += (size_t)NN * NH3 * 4;           // 1 MB

    // conversions
    k_f32_to_bf16<<<(NN * FIN / 4 + 255) / 256, 256, 0, stream>>>(x, xb, NN * FIN);
    k_cvt_watt<<<(512 * 512 + 255) / 256, 256, 0, stream>>>(W_att, Wattb);
    k_cvt_T<<<(512 * 256 + 255) / 256, 256, 0, stream>>>(W1, W1t, NH * NH1, NH2);
    k_cvt_T<<<(256 * 64 + 255) / 256, 256, 0, stream>>>(W2, W2t, NH2, NH3);
    // CSR: block per row
    k_build_csr<<<NN, 256, 0, stream>>>(adj, nbr, cnt);
    // Whc(f32) + Whb(bf16) = x @ Wcat  (4096 x 512, K=512)
    k_gemm_bf16<2><<<dim3((NH * NH1) / GBN, NN / GBM), 256, 0, stream>>>(xb, Wattb, Whc, Whb, NN, NH * NH1, FIN);
    // scores (fp32)
    k_scores<<<NN, 256, 0, stream>>>(Whc, a, s1, s2);
    // attention -> xrb (bf16), gathers Whb
    k_attn<<<NN, 256, 0, stream>>>(Whb, s1, s2, nbr, cnt, xrb);
    // y1b(bf16) = xr @ W1  (4096 x 256, K=512)
    k_gemm_bf16<1><<<dim3(NH2 / GBN, NN / GBM), 256, 0, stream>>>(xrb, W1t, nullptr, y1b, NN, NH2, NH * NH1);
    // g1 = relu(nbrsum(y1b)) -> bf16
    k_nbr_sum_bf<<<NN, 256, 0, stream>>>(y1b, nbr, cnt, g1b, NH2);
    // y2 = g1 @ W2  (4096 x 64, K=256)
    k_gemm_bf16<0><<<dim3(NH3 / GBN, NN / GBM), 256, 0, stream>>>(g1b, W2t, y2, nullptr, NN, NH3, NH2);
    // g2 + softmax
    k_final<<<NN, 64, 0, stream>>>(y2, nbr, cnt, out);
}